// Round 10
// baseline (210.723 us; speedup 1.0000x reference)
//
#include <hip/hip_runtime.h>
#include <hip/hip_fp16.h>
#include <stdint.h>

typedef __attribute__((ext_vector_type(4))) int int32x4;
typedef __attribute__((ext_vector_type(4))) float float32x4;

#define TOKENS 8192
#define IN_F   4096
#define OUT_F  4096
#define BM 256
#define BN 256
#define BK 64               // int8 per K-step = 64 B rows (bank-uniform, no swizzle)
#define NSTEP (IN_F / BK)   // 64 K-steps
#define ESTR 260            // epilogue LDS row stride (f32): 2-way bank alias = free

#define AS1 __attribute__((address_space(1)))
#define AS3 __attribute__((address_space(3)))

// ------- fused pack: int32->int8 for x and w, plus bias tuple-output -------
__global__ __launch_bounds__(256)
void pack_all_kernel(const int* __restrict__ x32, const int* __restrict__ w32,
                     const float* __restrict__ bias,
                     uint32_t* __restrict__ x8, uint32_t* __restrict__ w8,
                     float* __restrict__ bias_out)
{
    const int gid = blockIdx.x * 256 + threadIdx.x;
    if (gid < OUT_F / 4)
        ((float32x4*)bias_out)[gid] = ((const float32x4*)bias)[gid];

    const int nx4 = TOKENS * IN_F / 4;
    const int nw4 = OUT_F * IN_F / 4;
    for (int i = gid; i < nx4 + nw4; i += gridDim.x * 256) {
        const int* s; uint32_t* d; int j;
        if (i < nx4) { s = x32; d = x8; j = i; }
        else         { s = w32; d = w8; j = i - nx4; }
        int32x4 v = ((const int32x4*)s)[j];               // 16 B/lane coalesced
        d[j] = (uint32_t)(v[0] & 0xff) | ((uint32_t)(v[1] & 0xff) << 8) |
               ((uint32_t)(v[2] & 0xff) << 16) | ((uint32_t)v[3] << 24);
    }
}

// ---- 256x256 i8 GEMM: BK=64, 4-buffer LDS ring, 3-step prefetch lead ------
// 512 threads = 8 waves; per wave 64 rows x 128 cols = 2MHx2mi x 2NHx4ni
// 16x16x64 fragments, 32 MFMA per step. Per step: 12 ds_read_b128 + 4
// global_load_lds (step t+3 -> ring buf) + vmcnt(8) + 1 barrier pair.
// Ring depth 4 => issue-to-consume distance 3 steps (covers L3 latency).
__global__ __launch_bounds__(512, 2)
void w8a8_gemm_kernel(const int8_t* __restrict__ x,
                      const int8_t* __restrict__ w,
                      const float* __restrict__ scale,
                      const float* __restrict__ bias,
                      float* __restrict__ out)
{
    __shared__ int8_t smem[131072];        // lA ring 64 KB | lB ring 64 KB ; epilogue reuse
    int8_t* lA = smem;                     // [4][256][64]
    int8_t* lB = smem + 65536;             // [4][256][64]

    const int tid = threadIdx.x;
    const int wv  = tid >> 6;
    const int l   = tid & 63;
    const int wqm = wv >> 1;               // 0..3  (32-row strip within 128-row half)
    const int wqn = wv & 1;                // 0..1  (64-col strip within 128-col half)

    // XCD-chunked bijective swizzle: 512 blocks = 8 XCDs x (8bn x 8bm) chunk
    const int xc  = blockIdx.x & 7;
    const int idx = blockIdx.x >> 3;
    const int bn  = (xc & 1) * 8 + (idx & 7);    // 0..15
    const int bm  = (xc >> 1) * 8 + (idx >> 3);  // 0..31

    const int8_t* baseA = x + (size_t)bm * BM * IN_F;
    const int8_t* baseB = w + (size_t)bn * BN * IN_F;

    // staging: one gload round = 512 thr x 16 B = 8 KB = 128 rows of 64 B.
    // thread -> row tid>>2, byte (tid&3)*16; LDS dest = base + tid*16 (linear/wave).
    const int   srow  = tid >> 2;
    const int   sbyte = (tid & 3) << 4;
    const int8_t* pA0 = baseA + (size_t)srow * IN_F + sbyte;
    const int8_t* pA1 = baseA + (size_t)(srow + 128) * IN_F + sbyte;
    const int8_t* pB0 = baseB + (size_t)srow * IN_F + sbyte;
    const int8_t* pB1 = baseB + (size_t)(srow + 128) * IN_F + sbyte;
    const int   dofs  = tid << 4;

    // fragment read addressing (round-4-verified 16x16x64 mapping)
    const int fr  = l & 15;
    const int cb0 = (l >> 4) << 4;         // k-bytes 0,16,32,48

    int32x4 acc[2][2][2][4];
#pragma unroll
    for (int a0 = 0; a0 < 2; ++a0)
#pragma unroll
        for (int a1 = 0; a1 < 2; ++a1)
#pragma unroll
            for (int a2 = 0; a2 < 2; ++a2)
#pragma unroll
                for (int a3 = 0; a3 < 4; ++a3)
                    acc[a0][a1][a2][a3] = (int32x4){0, 0, 0, 0};

    int32x4 aF[2][2];      // MH x mi
    int32x4 bF[2][4];      // NH x ni

    auto stage_step = [&](int t) {
        const int b = t & 3;
        int8_t* dA = lA + b * 16384;
        int8_t* dB = lB + b * 16384;
        const size_t co = (size_t)t * BK;
        __builtin_amdgcn_global_load_lds((const AS1 void*)(pA0 + co),
                                         (AS3 void*)(dA + dofs), 16, 0, 0);
        __builtin_amdgcn_global_load_lds((const AS1 void*)(pA1 + co),
                                         (AS3 void*)(dA + 8192 + dofs), 16, 0, 0);
        __builtin_amdgcn_global_load_lds((const AS1 void*)(pB0 + co),
                                         (AS3 void*)(dB + dofs), 16, 0, 0);
        __builtin_amdgcn_global_load_lds((const AS1 void*)(pB1 + co),
                                         (AS3 void*)(dB + 8192 + dofs), 16, 0, 0);
    };

    // ---- prologue: stage steps 0,1,2 (ring fills; 12 loads in flight) ----
    stage_step(0); stage_step(1); stage_step(2);
    asm volatile("s_waitcnt vmcnt(8)" ::: "memory");   // step 0 landed
    __builtin_amdgcn_s_barrier();

    // ---- main loop: 64 K-steps ----
    for (int t = 0; t < NSTEP; ++t) {
        const int8_t* lAb = lA + (t & 3) * 16384;
        const int8_t* lBb = lB + (t & 3) * 16384;

        // 12 ds_read_b128: A 4 frags, B 8 frags
#pragma unroll
        for (int MH = 0; MH < 2; ++MH)
#pragma unroll
            for (int mi = 0; mi < 2; ++mi)
                aF[MH][mi] = *(const int32x4*)&lAb[(MH * 128 + wqm * 32 + mi * 16 + fr) * 64 + cb0];
#pragma unroll
        for (int NH = 0; NH < 2; ++NH)
#pragma unroll
            for (int ni = 0; ni < 4; ++ni)
                bF[NH][ni] = *(const int32x4*)&lBb[(NH * 128 + wqn * 64 + ni * 16 + fr) * 64 + cb0];

        if (t + 3 < NSTEP) stage_step(t + 3);          // ring: 3-step lead

        if (t + 3 < NSTEP)      asm volatile("s_waitcnt vmcnt(8)" ::: "memory");
        else if (t + 2 < NSTEP) asm volatile("s_waitcnt vmcnt(4)" ::: "memory");
        else if (t + 1 < NSTEP) asm volatile("s_waitcnt vmcnt(0)" ::: "memory");

        __builtin_amdgcn_s_barrier();
        asm volatile("s_waitcnt lgkmcnt(0)" ::: "memory");
        __builtin_amdgcn_s_setprio(1);
#pragma unroll
        for (int MH = 0; MH < 2; ++MH)
#pragma unroll
            for (int NH = 0; NH < 2; ++NH)
#pragma unroll
                for (int mi = 0; mi < 2; ++mi)
#pragma unroll
                    for (int ni = 0; ni < 4; ++ni)
                        acc[MH][NH][mi][ni] = __builtin_amdgcn_mfma_i32_16x16x64_i8(
                            aF[MH][mi], bF[NH][ni], acc[MH][NH][mi][ni], 0, 0, 0);
        __builtin_amdgcn_s_setprio(0);
        __builtin_amdgcn_s_barrier();
    }

    // ---- epilogue: LDS-staged, fully coalesced float4 stores (round-8-verified) ----
    __syncthreads();
    int* eL = (int*)smem;
    const int c4   = tid & 63;          // float4 col index within 256-col block
    const int rowt = tid >> 6;          // 0..7
    const float32x4 sc4 = ((const float32x4*)scale)[bn * 64 + c4];
    const float32x4 bf4 = ((const float32x4*)bias )[bn * 64 + c4];
    const __half bh[4] = { __float2half(bf4[0]), __float2half(bf4[1]),
                           __float2half(bf4[2]), __float2half(bf4[3]) };
    const int r0 = (l >> 4) << 2;
    const int wr0 = (wqm & 1) * 32 + r0;

    for (int c = 0; c < 4; ++c) {
        if ((wqm >> 1) == (c & 1)) {
            const int MH = c >> 1;
#pragma unroll
            for (int NH = 0; NH < 2; ++NH)
#pragma unroll
                for (int mi = 0; mi < 2; ++mi)
#pragma unroll
                    for (int ni = 0; ni < 4; ++ni)
#pragma unroll
                        for (int r = 0; r < 4; ++r)
                            eL[(wr0 + mi * 16 + r) * ESTR +
                               NH * 128 + wqn * 64 + ni * 16 + fr] = acc[MH][NH][mi][ni][r];
        }
        __syncthreads();
#pragma unroll
        for (int p = 0; p < 8; ++p) {
            const int rl = p * 8 + rowt;
            int32x4 v = *(const int32x4*)&eL[rl * ESTR + c4 * 4];
            float32x4 o;
#pragma unroll
            for (int j = 0; j < 4; ++j) {
                __half h = __float2half((float)v[j] * sc4[j]);
                o[j] = __half2float(__hadd(h, bh[j]));
            }
            const size_t rowg = (size_t)(bm * 256 + c * 64 + rl);
            ((float32x4*)out)[rowg * (OUT_F / 4) + bn * 64 + c4] = o;
        }
        __syncthreads();   // copy-out done before next chunk overwrites
    }
}

extern "C" void kernel_launch(void* const* d_in, const int* in_sizes, int n_in,
                              void* d_out, int out_size, void* d_ws, size_t ws_size,
                              hipStream_t stream)
{
    const int*   x32   = (const int*)d_in[0];
    const int*   w32   = (const int*)d_in[1];
    const float* scale = (const float*)d_in[2];
    const float* bias  = (const float*)d_in[3];
    float* out = (float*)d_out;

    int8_t* x8 = (int8_t*)d_ws;
    int8_t* w8 = x8 + (size_t)TOKENS * IN_F;

    pack_all_kernel<<<3072, 256, 0, stream>>>(x32, w32, bias, (uint32_t*)x8, (uint32_t*)w8,
                                              out + (size_t)TOKENS * OUT_F);

    w8a8_gemm_kernel<<<512, 512, 0, stream>>>(x8, w8, scale, bias, out);
}

// Round 11
// 189.106 us; speedup vs baseline: 1.1143x; 1.1143x over previous
//
#include <hip/hip_runtime.h>
#include <hip/hip_fp16.h>
#include <stdint.h>

typedef __attribute__((ext_vector_type(4))) int int32x4;
typedef __attribute__((ext_vector_type(4))) float float32x4;

#define TOKENS 8192
#define IN_F   4096
#define OUT_F  4096
#define BM 256
#define BN 256
#define BK 128              // int8 per K-tile = 128 B rows
#define NT (IN_F / BK)      // 32 K-tiles
#define ESTR 260            // epilogue LDS row stride (f32): 2-way bank alias = free

#define AS1 __attribute__((address_space(1)))
#define AS3 __attribute__((address_space(3)))

// ------- fused pack: int32->int8 for x and w, plus bias tuple-output -------
__global__ __launch_bounds__(256)
void pack_all_kernel(const int* __restrict__ x32, const int* __restrict__ w32,
                     const float* __restrict__ bias,
                     uint32_t* __restrict__ x8, uint32_t* __restrict__ w8,
                     float* __restrict__ bias_out)
{
    const int gid = blockIdx.x * 256 + threadIdx.x;
    if (gid < OUT_F / 4) {
        float32x4 b4 = __builtin_nontemporal_load((const float32x4*)bias + gid);
        __builtin_nontemporal_store(b4, (float32x4*)bias_out + gid);
    }

    const int nx4 = TOKENS * IN_F / 4;
    const int nw4 = OUT_F * IN_F / 4;
    for (int i = gid; i < nx4 + nw4; i += gridDim.x * 256) {
        const int* s; uint32_t* d; int j;
        if (i < nx4) { s = x32; d = x8; j = i; }
        else         { s = w32; d = w8; j = i - nx4; }
        // nt load: 192 MB read-once int32 must not evict x8/w8 from L2/L3
        int32x4 v = __builtin_nontemporal_load((const int32x4*)s + j);
        d[j] = (uint32_t)(v[0] & 0xff) | ((uint32_t)(v[1] & 0xff) << 8) |
               ((uint32_t)(v[2] & 0xff) << 16) | ((uint32_t)v[3] << 24);
    }
}

// --------- 256x256 i8 GEMM, counted-vmcnt two-phase schedule (r9) ----------
// + XCD-chunked block swizzle (r10-proven FETCH cut) + nt epilogue stores.
__global__ __launch_bounds__(512, 2)
void w8a8_gemm_kernel(const int8_t* __restrict__ x,
                      const int8_t* __restrict__ w,
                      const float* __restrict__ scale,
                      const float* __restrict__ bias,
                      float* __restrict__ out)
{
    __shared__ int8_t smem[131072];            // staging: lA | lB ; epilogue reuse
    int8_t* lA = smem;                         // [buf][half][128][128B] 64 KB
    int8_t* lB = smem + 65536;                 // 64 KB

    const int tid = threadIdx.x;
    const int wv  = tid >> 6;
    const int l   = tid & 63;
    const int wqm = wv >> 1;               // 0..3  (32-row strip within 128-row half)
    const int wqn = wv & 1;                // 0..1  (64-col strip within 128-col half)

    // XCD-chunked bijective swizzle: 512 blocks = 8 XCDs x (8bn x 8bm) chunk.
    // Within an XCD bn varies fastest: 8 consecutive blocks share the A-panel
    // (1 MB, L2-resident) and sweep 8 B-slices (4 MB = one XCD L2).
    const int xc  = blockIdx.x & 7;
    const int idx = blockIdx.x >> 3;
    const int bn  = (xc & 1) * 8 + (idx & 7);    // 0..15
    const int bm  = (xc >> 1) * 8 + (idx >> 3);  // 0..31

    const int8_t* baseA = x + (size_t)bm * BM * IN_F;
    const int8_t* baseB = w + (size_t)bn * BN * IN_F;

    // staging: T2 swizzle via pre-swizzled global source (rule 21)
    const int seg0 = wv * 2, seg1 = wv * 2 + 1;   // 16 segs x 8 rows per half
    const int r8   = l >> 3;
    const int swc  = (((l & 7) ^ r8) << 4);

    // hoisted per-thread staging source pointers (A/B x seg0/seg1)
    const int8_t* pA0 = baseA + (size_t)(seg0 * 8 + r8) * IN_F + swc;
    const int8_t* pA1 = baseA + (size_t)(seg1 * 8 + r8) * IN_F + swc;
    const int8_t* pB0 = baseB + (size_t)(seg0 * 8 + r8) * IN_F + swc;
    const int8_t* pB1 = baseB + (size_t)(seg1 * 8 + r8) * IN_F + swc;

    // fragment read addressing
    const int fr  = l & 15;
    const int xk  = (l & 7) << 4;
    const int cb0 = (l >> 4) << 4;

    int32x4 acc[2][2][2][4];
#pragma unroll
    for (int a0 = 0; a0 < 2; ++a0)
#pragma unroll
        for (int a1 = 0; a1 < 2; ++a1)
#pragma unroll
            for (int a2 = 0; a2 < 2; ++a2)
#pragma unroll
                for (int a3 = 0; a3 < 4; ++a3)
                    acc[a0][a1][a2][a3] = (int32x4){0, 0, 0, 0};

    int32x4 aF[2][2];      // 2 mi x 2 ks
    int32x4 bF0[4][2];     // B half 0 frags (live across both phases)
    int32x4 bF1[4][2];     // B half 1 frags

    // stage one half-tile: h4 = tile*4 + {0:A0 1:A1 2:B0 3:B1}
    auto stage_half = [&](int h4) {
        const int kt_ = h4 >> 2;
        const int wh_ = h4 & 3;
        const size_t off = (size_t)(wh_ & 1) * (128 * IN_F) + (size_t)kt_ * BK;
        const int8_t* s0 = ((wh_ < 2) ? pA0 : pB0) + off;
        const int8_t* s1 = ((wh_ < 2) ? pA1 : pB1) + off;
        int8_t* db = ((wh_ < 2) ? lA : lB) + ((kt_ & 1) << 15) + ((wh_ & 1) << 14);
        __builtin_amdgcn_global_load_lds(
            (const AS1 void*)s0, (AS3 void*)(db + seg0 * 1024), 16, 0, 0);
        __builtin_amdgcn_global_load_lds(
            (const AS1 void*)s1, (AS3 void*)(db + seg1 * 1024), 16, 0, 0);
    };

#define LDA(MH)                                                                        \
    do {                                                                               \
        _Pragma("unroll") for (int mi = 0; mi < 2; ++mi)                               \
        _Pragma("unroll") for (int ks = 0; ks < 2; ++ks)                               \
            aF[mi][ks] = *(const int32x4*)&lAb[((MH) << 14) +                          \
                (wqm * 32 + mi * 16 + fr) * 128 + (((ks * 64) + cb0) ^ xk)];           \
    } while (0)

#define LDB(NH, DST)                                                                   \
    do {                                                                               \
        _Pragma("unroll") for (int ni = 0; ni < 4; ++ni)                               \
        _Pragma("unroll") for (int ks = 0; ks < 2; ++ks)                               \
            DST[ni][ks] = *(const int32x4*)&lBb[((NH) << 14) +                         \
                (wqn * 64 + ni * 16 + fr) * 128 + (((ks * 64) + cb0) ^ xk)];           \
    } while (0)

#define MMAQ(MH, NH, BF)                                                               \
    do {                                                                               \
        _Pragma("unroll") for (int mi = 0; mi < 2; ++mi)                               \
        _Pragma("unroll") for (int ni = 0; ni < 4; ++ni)                               \
        _Pragma("unroll") for (int ks = 0; ks < 2; ++ks)                               \
            acc[MH][NH][mi][ni] = __builtin_amdgcn_mfma_i32_16x16x64_i8(               \
                aF[mi][ks], BF[ni][ks], acc[MH][NH][mi][ni], 0, 0, 0);                 \
    } while (0)

    // ---- prologue: tile0 (A0,A1,B0,B1) + A0(1) ----
    stage_half(0); stage_half(1); stage_half(2); stage_half(3);
    stage_half(4);
    asm volatile("s_waitcnt vmcnt(2)" ::: "memory");   // tile0 landed; A0(1) in flight
    __builtin_amdgcn_s_barrier();

    // ---- main loop: 2 phases per K-tile ----
    for (int t = 0; t < NT; ++t) {
        const int8_t* lAb = lA + ((t & 1) << 15);
        const int8_t* lBb = lB + ((t & 1) << 15);

        // phase 0: C rows 0..127 (both B halves)
        LDA(0); LDB(0, bF0); LDB(1, bF1);               // 20 ds_read_b128
        if (t + 1 < NT) {                               // slot1 -> other parity
            stage_half(4 * (t + 1) + 1);                // A1(t+1)
            stage_half(4 * (t + 1) + 2);                // B0(t+1)
            stage_half(4 * (t + 1) + 3);                // B1(t+1)
        }
        __builtin_amdgcn_s_barrier();
        asm volatile("s_waitcnt lgkmcnt(0)" ::: "memory");
        __builtin_amdgcn_s_setprio(1);
        MMAQ(0, 0, bF0); MMAQ(0, 1, bF1);               // 32 MFMA
        __builtin_amdgcn_s_setprio(0);
        __builtin_amdgcn_s_barrier();

        // phase 1: C rows 128..255 (A0(t) reads all completed at PH0 close)
        LDA(1);                                         // 4 ds_read_b128
        if (t + 2 < NT) stage_half(4 * (t + 2) + 0);    // slot2: A0(t+2) -> live parity
        if (t + 2 < NT)      asm volatile("s_waitcnt vmcnt(2)" ::: "memory");
        else if (t + 1 < NT) asm volatile("s_waitcnt vmcnt(0)" ::: "memory");
        __builtin_amdgcn_s_barrier();
        asm volatile("s_waitcnt lgkmcnt(0)" ::: "memory");
        __builtin_amdgcn_s_setprio(1);
        MMAQ(1, 0, bF0); MMAQ(1, 1, bF1);               // 32 MFMA
        __builtin_amdgcn_s_setprio(0);
        __builtin_amdgcn_s_barrier();
    }

    // ---- epilogue: LDS-staged, fully coalesced float4 nt stores ----
    __syncthreads();
    int* eL = (int*)smem;
    const int c4   = tid & 63;          // float4 col index within 256-col block
    const int rowt = tid >> 6;          // 0..7
    const float32x4 sc4 = ((const float32x4*)scale)[bn * 64 + c4];
    const float32x4 bf4 = ((const float32x4*)bias )[bn * 64 + c4];
    const __half bh[4] = { __float2half(bf4[0]), __float2half(bf4[1]),
                           __float2half(bf4[2]), __float2half(bf4[3]) };
    const int r0 = (l >> 4) << 2;
    const int wr0 = (wqm & 1) * 32 + r0;

    for (int c = 0; c < 4; ++c) {
        if ((wqm >> 1) == (c & 1)) {
            const int MH = c >> 1;
#pragma unroll
            for (int NH = 0; NH < 2; ++NH)
#pragma unroll
                for (int mi = 0; mi < 2; ++mi)
#pragma unroll
                    for (int ni = 0; ni < 4; ++ni)
#pragma unroll
                        for (int r = 0; r < 4; ++r)
                            eL[(wr0 + mi * 16 + r) * ESTR +
                               NH * 128 + wqn * 64 + ni * 16 + fr] = acc[MH][NH][mi][ni][r];
        }
        __syncthreads();
#pragma unroll
        for (int p = 0; p < 8; ++p) {
            const int rl = p * 8 + rowt;
            int32x4 v = *(const int32x4*)&eL[rl * ESTR + c4 * 4];
            float32x4 o;
#pragma unroll
            for (int j = 0; j < 4; ++j) {
                __half h = __float2half((float)v[j] * sc4[j]);
                o[j] = __half2float(__hadd(h, bh[j]));
            }
            const size_t rowg = (size_t)(bm * 256 + c * 64 + rl);
            // nt store: output is never re-read; keep L2 for A/B panels
            __builtin_nontemporal_store(o, (float32x4*)out + rowg * (OUT_F / 4) + bn * 64 + c4);
        }
        __syncthreads();   // copy-out done before next chunk overwrites
    }
#undef LDA
#undef LDB
#undef MMAQ
}

extern "C" void kernel_launch(void* const* d_in, const int* in_sizes, int n_in,
                              void* d_out, int out_size, void* d_ws, size_t ws_size,
                              hipStream_t stream)
{
    const int*   x32   = (const int*)d_in[0];
    const int*   w32   = (const int*)d_in[1];
    const float* scale = (const float*)d_in[2];
    const float* bias  = (const float*)d_in[3];
    float* out = (float*)d_out;

    int8_t* x8 = (int8_t*)d_ws;
    int8_t* w8 = x8 + (size_t)TOKENS * IN_F;

    pack_all_kernel<<<3072, 256, 0, stream>>>(x32, w32, bias, (uint32_t*)x8, (uint32_t*)w8,
                                              out + (size_t)TOKENS * OUT_F);

    w8a8_gemm_kernel<<<512, 512, 0, stream>>>(x8, w8, scale, bias, out);
}

// Round 12
// 185.942 us; speedup vs baseline: 1.1333x; 1.0170x over previous
//
#include <hip/hip_runtime.h>
#include <hip/hip_fp16.h>
#include <stdint.h>

typedef __attribute__((ext_vector_type(4))) int int32x4;
typedef __attribute__((ext_vector_type(4))) float float32x4;

#define TOKENS 8192
#define IN_F   4096
#define OUT_F  4096
#define BM 256
#define BN 256
#define BK 128              // int8 per K-tile = 128 B rows
#define NT (IN_F / BK)      // 32 K-tiles
#define ESTR 260            // epilogue LDS row stride (f32): 2-way bank alias = free

#define AS1 __attribute__((address_space(1)))
#define AS3 __attribute__((address_space(3)))

// ------- fused pack: int32->int8 for x and w, plus bias tuple-output -------
__global__ __launch_bounds__(256)
void pack_all_kernel(const int* __restrict__ x32, const int* __restrict__ w32,
                     const float* __restrict__ bias,
                     uint32_t* __restrict__ x8, uint32_t* __restrict__ w8,
                     float* __restrict__ bias_out)
{
    const int gid = blockIdx.x * 256 + threadIdx.x;
    if (gid < OUT_F / 4) {
        float32x4 b4 = __builtin_nontemporal_load((const float32x4*)bias + gid);
        __builtin_nontemporal_store(b4, (float32x4*)bias_out + gid);
    }

    const int nx4 = TOKENS * IN_F / 4;
    const int nw4 = OUT_F * IN_F / 4;
    for (int i = gid; i < nx4 + nw4; i += gridDim.x * 256) {
        const int* s; uint32_t* d; int j;
        if (i < nx4) { s = x32; d = x8; j = i; }
        else         { s = w32; d = w8; j = i - nx4; }
        int32x4 v = __builtin_nontemporal_load((const int32x4*)s + j);
        d[j] = (uint32_t)(v[0] & 0xff) | ((uint32_t)(v[1] & 0xff) << 8) |
               ((uint32_t)(v[2] & 0xff) << 16) | ((uint32_t)v[3] << 24);
    }
}

// ---- 256x256 i8 GEMM: single-phase tile, compiler-overlapped ds->MFMA -----
// 512 threads = 8 waves (4M x 2N). Per tile: 24 ds_read_b128 (all frags) +
// 8 global_load_lds (full tile t+1 -> other parity) + 64 MFMA + vmcnt(0) +
// ONE barrier. No manual lgkmcnt: the compiler emits counted lgkmcnt so the
// later ds_reads complete under the first MFMA quadrant (m97 behavior).
// Race-free: reads of tile t drain before tile t's closing barrier (compiler
// waits before last MFMA); staging of t+2 (parity t) issues after it.
__global__ __launch_bounds__(512, 2)
void w8a8_gemm_kernel(const int8_t* __restrict__ x,
                      const int8_t* __restrict__ w,
                      const float* __restrict__ scale,
                      const float* __restrict__ bias,
                      float* __restrict__ out)
{
    __shared__ int8_t smem[131072];            // staging: lA | lB ; epilogue reuse
    int8_t* lA = smem;                         // [buf][half][128][128B] 64 KB
    int8_t* lB = smem + 65536;                 // 64 KB

    const int tid = threadIdx.x;
    const int wv  = tid >> 6;
    const int l   = tid & 63;
    const int wqm = wv >> 1;               // 0..3  (32-row strip within 128-row half)
    const int wqn = wv & 1;                // 0..1  (64-col strip within 128-col half)

    // XCD-chunked bijective swizzle (r10-proven): 512 blocks = 8 XCDs x (8bn x 8bm)
    const int xc  = blockIdx.x & 7;
    const int idx = blockIdx.x >> 3;
    const int bn  = (xc & 1) * 8 + (idx & 7);    // 0..15
    const int bm  = (xc >> 1) * 8 + (idx >> 3);  // 0..31

    const int8_t* baseA = x + (size_t)bm * BM * IN_F;
    const int8_t* baseB = w + (size_t)bn * BN * IN_F;

    // staging: T2 swizzle via pre-swizzled global source (rule 21)
    const int seg0 = wv * 2, seg1 = wv * 2 + 1;   // 16 segs x 8 rows per half
    const int r8   = l >> 3;
    const int swc  = (((l & 7) ^ r8) << 4);

    const int8_t* pA0 = baseA + (size_t)(seg0 * 8 + r8) * IN_F + swc;
    const int8_t* pA1 = baseA + (size_t)(seg1 * 8 + r8) * IN_F + swc;
    const int8_t* pB0 = baseB + (size_t)(seg0 * 8 + r8) * IN_F + swc;
    const int8_t* pB1 = baseB + (size_t)(seg1 * 8 + r8) * IN_F + swc;

    // fragment read addressing
    const int fr  = l & 15;
    const int xk  = (l & 7) << 4;
    const int cb0 = (l >> 4) << 4;

    int32x4 acc[2][2][2][4];
#pragma unroll
    for (int a0 = 0; a0 < 2; ++a0)
#pragma unroll
        for (int a1 = 0; a1 < 2; ++a1)
#pragma unroll
            for (int a2 = 0; a2 < 2; ++a2)
#pragma unroll
                for (int a3 = 0; a3 < 4; ++a3)
                    acc[a0][a1][a2][a3] = (int32x4){0, 0, 0, 0};

    int32x4 aF[2][2][2];   // [MH][mi][ks]
    int32x4 bF[2][4][2];   // [NH][ni][ks]

    // stage one half-tile: h4 = tile*4 + {0:A0 1:A1 2:B0 3:B1}
    auto stage_half = [&](int h4) {
        const int kt_ = h4 >> 2;
        const int wh_ = h4 & 3;
        const size_t off = (size_t)(wh_ & 1) * (128 * IN_F) + (size_t)kt_ * BK;
        const int8_t* s0 = ((wh_ < 2) ? pA0 : pB0) + off;
        const int8_t* s1 = ((wh_ < 2) ? pA1 : pB1) + off;
        int8_t* db = ((wh_ < 2) ? lA : lB) + ((kt_ & 1) << 15) + ((wh_ & 1) << 14);
        __builtin_amdgcn_global_load_lds(
            (const AS1 void*)s0, (AS3 void*)(db + seg0 * 1024), 16, 0, 0);
        __builtin_amdgcn_global_load_lds(
            (const AS1 void*)s1, (AS3 void*)(db + seg1 * 1024), 16, 0, 0);
    };

#define LDA(MH)                                                                        \
    do {                                                                               \
        _Pragma("unroll") for (int mi = 0; mi < 2; ++mi)                               \
        _Pragma("unroll") for (int ks = 0; ks < 2; ++ks)                               \
            aF[MH][mi][ks] = *(const int32x4*)&lAb[((MH) << 14) +                      \
                (wqm * 32 + mi * 16 + fr) * 128 + (((ks * 64) + cb0) ^ xk)];           \
    } while (0)

#define LDB(NH)                                                                        \
    do {                                                                               \
        _Pragma("unroll") for (int ni = 0; ni < 4; ++ni)                               \
        _Pragma("unroll") for (int ks = 0; ks < 2; ++ks)                               \
            bF[NH][ni][ks] = *(const int32x4*)&lBb[((NH) << 14) +                      \
                (wqn * 64 + ni * 16 + fr) * 128 + (((ks * 64) + cb0) ^ xk)];           \
    } while (0)

#define MMAQ(MH, NH)                                                                   \
    do {                                                                               \
        _Pragma("unroll") for (int mi = 0; mi < 2; ++mi)                               \
        _Pragma("unroll") for (int ni = 0; ni < 4; ++ni)                               \
        _Pragma("unroll") for (int ks = 0; ks < 2; ++ks)                               \
            acc[MH][NH][mi][ni] = __builtin_amdgcn_mfma_i32_16x16x64_i8(               \
                aF[MH][mi][ks], bF[NH][ni][ks], acc[MH][NH][mi][ni], 0, 0, 0);         \
    } while (0)

    // ---- prologue: tile 0 fully staged ----
    stage_half(0); stage_half(1); stage_half(2); stage_half(3);
    asm volatile("s_waitcnt vmcnt(0)" ::: "memory");
    __builtin_amdgcn_s_barrier();

    // ---- main loop: ONE phase per K-tile ----
    for (int t = 0; t < NT; ++t) {
        const int8_t* lAb = lA + ((t & 1) << 15);
        const int8_t* lBb = lB + ((t & 1) << 15);

        // all 24 fragment reads, first-needed first (compiler emits counted lgkmcnt)
        LDA(0); LDB(0); LDB(1); LDA(1);

        // full tile t+1 -> other parity (in flight during the MFMA burst)
        if (t + 1 < NT) {
            stage_half(4 * (t + 1) + 0); stage_half(4 * (t + 1) + 1);
            stage_half(4 * (t + 1) + 2); stage_half(4 * (t + 1) + 3);
        }

        __builtin_amdgcn_s_setprio(1);
        MMAQ(0, 0); MMAQ(0, 1); MMAQ(1, 0); MMAQ(1, 1);   // 64 MFMA
        __builtin_amdgcn_s_setprio(0);

        if (t + 1 < NT) asm volatile("s_waitcnt vmcnt(0)" ::: "memory"); // ~2600cy old
        __builtin_amdgcn_s_barrier();
    }

    // ---- epilogue: LDS-staged, fully coalesced float4 nt stores (r8-verified) ----
    __syncthreads();
    int* eL = (int*)smem;
    const int c4   = tid & 63;          // float4 col index within 256-col block
    const int rowt = tid >> 6;          // 0..7
    const float32x4 sc4 = ((const float32x4*)scale)[bn * 64 + c4];
    const float32x4 bf4 = ((const float32x4*)bias )[bn * 64 + c4];
    const __half bh[4] = { __float2half(bf4[0]), __float2half(bf4[1]),
                           __float2half(bf4[2]), __float2half(bf4[3]) };
    const int r0 = (l >> 4) << 2;
    const int wr0 = (wqm & 1) * 32 + r0;

    for (int c = 0; c < 4; ++c) {
        if ((wqm >> 1) == (c & 1)) {
            const int MH = c >> 1;
#pragma unroll
            for (int NH = 0; NH < 2; ++NH)
#pragma unroll
                for (int mi = 0; mi < 2; ++mi)
#pragma unroll
                    for (int ni = 0; ni < 4; ++ni)
#pragma unroll
                        for (int r = 0; r < 4; ++r)
                            eL[(wr0 + mi * 16 + r) * ESTR +
                               NH * 128 + wqn * 64 + ni * 16 + fr] = acc[MH][NH][mi][ni][r];
        }
        __syncthreads();
#pragma unroll
        for (int p = 0; p < 8; ++p) {
            const int rl = p * 8 + rowt;
            int32x4 v = *(const int32x4*)&eL[rl * ESTR + c4 * 4];
            float32x4 o;
#pragma unroll
            for (int j = 0; j < 4; ++j) {
                __half h = __float2half((float)v[j] * sc4[j]);
                o[j] = __half2float(__hadd(h, bh[j]));
            }
            const size_t rowg = (size_t)(bm * 256 + c * 64 + rl);
            __builtin_nontemporal_store(o, (float32x4*)out + rowg * (OUT_F / 4) + bn * 64 + c4);
        }
        __syncthreads();   // copy-out done before next chunk overwrites
    }
#undef LDA
#undef LDB
#undef MMAQ
}

extern "C" void kernel_launch(void* const* d_in, const int* in_sizes, int n_in,
                              void* d_out, int out_size, void* d_ws, size_t ws_size,
                              hipStream_t stream)
{
    const int*   x32   = (const int*)d_in[0];
    const int*   w32   = (const int*)d_in[1];
    const float* scale = (const float*)d_in[2];
    const float* bias  = (const float*)d_in[3];
    float* out = (float*)d_out;

    int8_t* x8 = (int8_t*)d_ws;
    int8_t* w8 = x8 + (size_t)TOKENS * IN_F;

    pack_all_kernel<<<3072, 256, 0, stream>>>(x32, w32, bias, (uint32_t*)x8, (uint32_t*)w8,
                                              out + (size_t)TOKENS * OUT_F);

    w8a8_gemm_kernel<<<512, 512, 0, stream>>>(x8, w8, scale, bias, out);
}